// Round 8
// baseline (135.033 us; speedup 1.0000x reference)
//
#include <hip/hip_runtime.h>

typedef unsigned short u16;
typedef unsigned int u32;
typedef __attribute__((ext_vector_type(8))) __bf16 bf16x8;
typedef __attribute__((ext_vector_type(4))) float f32x4;
typedef __attribute__((ext_vector_type(4))) u32 u32x4;
typedef __attribute__((ext_vector_type(4))) u16 u16x4;

#define DEV __device__ __forceinline__

constexpr int S_LEN = 2048;
constexpr int DMODEL = 1024;
constexpr int NHEAD = 16;
constexpr int ROWS = 4096;   // B*S
// fold 1/sqrt(64) * log2(e) into Q so softmax is exp2(s - B), B = 16
constexpr float QSCALE = 0.125f * 1.4426950408889634f;

DEV u16 f2bf(float f) {
  union { float f; u32 u; } v; v.f = f;
  u32 u = v.u;
  u32 r = (u + 0x7fffu + ((u >> 16) & 1u)) >> 16;  // RNE
  return (u16)r;
}
DEV float vexp2(float x) {
#if __has_builtin(__builtin_amdgcn_exp2f)
  return __builtin_amdgcn_exp2f(x);
#else
  return exp2f(x);
#endif
}
// async global->LDS, 16B per lane (m97 recipe)
DEV void gload_lds16(const u16* g, u16* l) {
  __builtin_amdgcn_global_load_lds((const __attribute__((address_space(1))) void*)g,
                                   (__attribute__((address_space(3))) void*)l, 16, 0, 0);
}
// XOR swizzle for [rows][64] u16 LDS tiles (row stride 128B), 8-col granules
DEV int swz(int r, int c) { return r * 64 + (c ^ ((r & 7) << 3)); }

// ---------------- fused fp32 -> bf16 convert for x, w_qkv, w_out ----------------
__global__ __launch_bounds__(256) void k_cvt_all(const float* __restrict__ x,
                                                 const float* __restrict__ wq,
                                                 const float* __restrict__ wo,
                                                 u16* __restrict__ xb,
                                                 u16* __restrict__ wqb,
                                                 u16* __restrict__ wob) {
  int i = blockIdx.x * 256 + threadIdx.x;  // 1048576 total (x8 elems)
  const float* in; u16* out; int off;
  if (i < 524288)       { in = x;  out = xb;  off = i; }
  else if (i < 917504)  { in = wq; out = wqb; off = i - 524288; }
  else                  { in = wo; out = wob; off = i - 917504; }
  const float4* p4 = (const float4*)in;
  float4 a = p4[2 * off], b = p4[2 * off + 1];
  alignas(16) u16 r[8] = {f2bf(a.x), f2bf(a.y), f2bf(a.z), f2bf(a.w),
                          f2bf(b.x), f2bf(b.y), f2bf(b.z), f2bf(b.w)};
  *(u32x4*)(out + 8 * off) = *(const u32x4*)r;
}

// ---------------- RoPE cos/sin table: [S][32] float2 (cos, sin) ----------------
__global__ __launch_bounds__(256) void k_rope_tab(const int* __restrict__ pos,
                                                  float2* __restrict__ tab) {
  int t = blockIdx.x * 256 + threadIdx.x;  // S*32 = 65536
  int s = t >> 5, fi = t & 31;
  float p = (float)pos[s];
  float invf = expf(-(float)fi * 0.28782313662425572f);  // 10000^(-fi/32)
  float ang = p * invf;
  tab[t] = float2{cosf(ang), sinf(ang)};
}

// ============== GEMM: 256x256, BK=64, 8 waves, 4-phase counted schedule =======
// Per K-tile T (buf b=T&1), 4 phases; phase = {stage 1 half-tile; ds_read quad
// frags; s_barrier; lgkmcnt(0); setprio(1); 16 MFMA; setprio(0); s_barrier}.
// Stage ring: ph0/ph1 stage T+1.B0/B1 (other buf); ph2/ph3 stage T+2.A0/A1 into
// the CURRENT buf's A-slots (read-once-into-regs at ph0/ph1 -> free). One
// vmcnt(4) per tile at ph3: retires all of T+1 (needed next tile), keeps
// T+2.A0/A1 (4 loads) in flight across the barriers. Frags register-cached:
// A read once per half (8 reads), reused across both nq phases.
// MODE 1: N=3072 QKV epilogue (RoPE-fused qk / transposed vt).
// MODE 0: N=1024 fp32 out.
template <int MODE>
__global__ __launch_bounds__(512, 2) void k_gemm8(const u16* __restrict__ A,
                                                  const u16* __restrict__ Bw,
                                                  void* __restrict__ Out,
                                                  u16* __restrict__ vt,
                                                  const float2* __restrict__ tab,
                                                  int NB) {
  __shared__ alignas(16) u16 As[2][16384];  // [buf][256][64], granule-swizzled
  __shared__ alignas(16) u16 Bs[2][16384];
  const int tid = threadIdx.x, lane = tid & 63;
  const int w = tid >> 6, wr = w >> 2, wc = w & 3;  // 2M x 4N waves
  const int l15 = lane & 15, l16 = lane >> 4;
  // bijective XCD swizzle (grid multiple of 8)
  const int cpx = gridDim.x >> 3;
  const int wg = (blockIdx.x & 7) * cpx + (blockIdx.x >> 3);
  const int mb = wg / NB, nb = wg - mb * NB;
  const int m0 = mb * 256, n0 = nb * 256;

  // staging: half-tile (128 rows x 64 cols) = 512 thr x 2 gload_lds x 16B.
  // LDS slot (row, granule gd) holds global granule gd^(row&7) [involution].
  const int str = tid >> 3;          // 0..63
  const int gd = tid & 7;
  const int gs = gd ^ (str & 7);
  const u16* aS = A + (size_t)(m0 + str) * 1024 + gs * 8;
  const u16* bS = Bw + (size_t)(n0 + str) * 1024 + gs * 8;
  const int dI = str * 64 + gd * 8;

#define STGA(T, h) do { \
    gload_lds16(aS + (size_t)((h) * 128) * 1024 + (T) * 64, &As[(T) & 1][(h) * 8192 + dI]); \
    gload_lds16(aS + (size_t)((h) * 128 + 64) * 1024 + (T) * 64, \
                &As[(T) & 1][(h) * 8192 + 4096 + dI]); \
  } while (0)
#define STGB(T, h) do { \
    gload_lds16(bS + (size_t)((h) * 128) * 1024 + (T) * 64, &Bs[(T) & 1][(h) * 8192 + dI]); \
    gload_lds16(bS + (size_t)((h) * 128 + 64) * 1024 + (T) * 64, \
                &Bs[(T) & 1][(h) * 8192 + 4096 + dI]); \
  } while (0)

  f32x4 acc[8][4] = {};
  const int xr = l15 & 7;
  const int rofs0 = ((l16 ^ xr)) * 8;        // k-half 0 granule slot
  const int rofs1 = (((4 + l16) ^ xr)) * 8;  // k-half 1
  bf16x8 Af[2][4][2], Bf[2][2];

#define RDA(mq) do { \
    _Pragma("unroll") \
    for (int m_ = 0; m_ < 4; m_++) { \
      const u16* p_ = &As[b][(wr * 128 + (mq) * 64 + m_ * 16 + l15) * 64]; \
      Af[mq][m_][0] = *(const bf16x8*)(p_ + rofs0); \
      Af[mq][m_][1] = *(const bf16x8*)(p_ + rofs1); \
    } \
  } while (0)
#define RDB(nq) do { \
    _Pragma("unroll") \
    for (int n_ = 0; n_ < 2; n_++) { \
      const u16* p_ = &Bs[b][(wc * 64 + (nq) * 32 + n_ * 16 + l15) * 64]; \
      Bf[n_][0] = *(const bf16x8*)(p_ + rofs0); \
      Bf[n_][1] = *(const bf16x8*)(p_ + rofs1); \
    } \
  } while (0)
#define MF(mq, nq) do { \
    __builtin_amdgcn_s_setprio(1); \
    _Pragma("unroll") \
    for (int m_ = 0; m_ < 4; m_++) \
      _Pragma("unroll") \
      for (int n_ = 0; n_ < 2; n_++) \
        _Pragma("unroll") \
        for (int k_ = 0; k_ < 2; k_++) \
          acc[(mq) * 4 + m_][(nq) * 2 + n_] = __builtin_amdgcn_mfma_f32_16x16x32_bf16( \
              Af[mq][m_][k_], Bf[n_][k_], acc[(mq) * 4 + m_][(nq) * 2 + n_], 0, 0, 0); \
    __builtin_amdgcn_s_setprio(0); \
  } while (0)
#define BARRIER() __builtin_amdgcn_s_barrier()
#define LGKM0() asm volatile("s_waitcnt lgkmcnt(0)" ::: "memory")

  // prologue: T0 fully + T1.A halves (6 stage-pairs = 12 loads in flight)
  STGA(0, 0); STGA(0, 1); STGB(0, 0); STGB(0, 1);
  STGA(1, 0); STGA(1, 1);
  asm volatile("s_waitcnt vmcnt(4)" ::: "memory");  // T0 landed; T1.A in flight
  BARRIER();

  for (int T = 0; T < 16; ++T) {
    const int b = T & 1;
    // ---- ph0: Q(0,0); stage T+1.B0 (other buf) ----
    if (T + 1 < 16) STGB(T + 1, 0);
    RDA(0); RDB(0);
    BARRIER(); LGKM0();
    MF(0, 0);
    BARRIER();
    // ---- ph1: Q(1,0); stage T+1.B1 ----
    if (T + 1 < 16) STGB(T + 1, 1);
    RDA(1);
    BARRIER(); LGKM0();
    MF(1, 0);
    BARRIER();
    // ---- ph2: Q(0,1); stage T+2.A0 into current buf (A0 slots free) ----
    if (T + 2 < 16) STGA(T + 2, 0);
    RDB(1);
    BARRIER(); LGKM0();
    MF(0, 1);
    BARRIER();
    // ---- ph3: Q(1,1); stage T+2.A1; counted vmcnt ----
    if (T + 2 < 16) STGA(T + 2, 1);
    if (T < 13) asm volatile("s_waitcnt vmcnt(4)" ::: "memory");  // retire T+1 fully
    else        asm volatile("s_waitcnt vmcnt(0)" ::: "memory");  // epilogue tiles
    BARRIER();
    MF(1, 1);
    BARRIER();
  }
#undef STGA
#undef STGB
#undef RDA
#undef RDB
#undef MF
#undef BARRIER
#undef LGKM0

  // epilogue — C/D layout (m89/m91): col = lane&15, row = (lane>>4)*4 + reg
  const int rb = m0 + wr * 128 + l16 * 4;
  const int cb = n0 + wc * 64 + l15;
  if (MODE == 0) {
    float* o = (float*)Out;
#pragma unroll
    for (int m = 0; m < 8; m++)
#pragma unroll
      for (int n = 0; n < 4; n++)
#pragma unroll
        for (int r = 0; r < 4; r++)
          o[(size_t)(rb + m * 16 + r) * 1024 + cb + n * 16] = acc[m][n][r];
  } else if (n0 >= 2048) {
    // V third -> vt[(b*1024 + hd)][s], 4 consecutive s per lane packed as 8B
#pragma unroll
    for (int m = 0; m < 8; m++)
#pragma unroll
      for (int n = 0; n < 4; n++) {
        int row = rb + m * 16, col = cb + n * 16;
        int bb = row >> 11, s = row & 2047, hd = col - 2048;
        u16x4 pk = {f2bf(acc[m][n][0]), f2bf(acc[m][n][1]),
                    f2bf(acc[m][n][2]), f2bf(acc[m][n][3])};
        *(u16x4*)&vt[(size_t)(bb * 1024 + hd) * S_LEN + s] = pk;
      }
  } else {
    // q,k thirds: fused RoPE (+QSCALE on q); adjacent lanes hold (even,odd) cols
    u16* qk = (u16*)Out;
    const bool isq = (n0 < 1024);
#pragma unroll
    for (int m = 0; m < 8; m++) {
      int row0 = rb + m * 16;
      int s0 = row0 & 2047;
#pragma unroll
      for (int n = 0; n < 4; n++) {
        int col = cb + n * 16;
        int fi = (col & 63) >> 1;
        bool odd = col & 1;
        f32x4 v = acc[m][n];
        f32x4 p;
#pragma unroll
        for (int r = 0; r < 4; r++) p[r] = __shfl_xor(v[r], 1);
#pragma unroll
        for (int r = 0; r < 4; r++) {
          float2 cs = tab[(s0 + r) * 32 + fi];
          float xe = odd ? p[r] : v[r];
          float xo = odd ? v[r] : p[r];
          float o = odd ? (xe * cs.y + xo * cs.x) : (xe * cs.x - xo * cs.y);
          if (isq) o *= QSCALE;
          qk[(size_t)(row0 + r) * 2048 + col] = f2bf(o);
        }
      }
    }
  }
}

// ---------------- causal flash attention, fixed-max exp2 softmax ----------------
// grid: (bh=32, j=32), qt = 31-j (LPT). 4 waves, wave w owns q rows
// [q0+16w, +16). KVBLK=64. lsum via MFMA-with-ones.
__global__ __launch_bounds__(256) void k_attn(const u16* __restrict__ qk,
                                              const u16* __restrict__ vt,
                                              u16* __restrict__ aout) {
  __shared__ alignas(16) u16 Ks[64 * 64];     // K tile [kv][d], swizzled
  __shared__ alignas(16) u16 Vs[64 * 64];     // V^T tile [d][kv], swizzled
  __shared__ alignas(16) u16 Ps[4][16 * 64];  // per-wave P [q][kv], swizzled
  const int tid = threadIdx.x, lane = tid & 63, w = tid >> 6;
  const int l15 = lane & 15, l16 = lane >> 4;
  const int qt = 31 - blockIdx.y;
  const int q0 = qt * 64;
  const int bh = blockIdx.x, b = bh >> 4, h = bh & 15;
  const u16* qbase = qk + (size_t)b * S_LEN * 2048 + h * 64;
  const u16* kbase = qbase + 1024;
  const u16* vbase = vt + (size_t)bh * 64 * S_LEN;
  const int wq0 = q0 + w * 16;

  bf16x8 qa[2];
#pragma unroll
  for (int kb = 0; kb < 2; kb++)
    qa[kb] = *(const bf16x8*)&qbase[(size_t)(wq0 + l15) * 2048 + kb * 32 + l16 * 8];

  bf16x8 vone;
#pragma unroll
  for (int j = 0; j < 8; j++) vone[j] = (__bf16)1.0f;

  f32x4 osum[4] = {};
  f32x4 osl = {};  // row-sum of P (all 16 cols identical)

  const int nt = qt + 1;  // 64-wide kv tiles
  const int srow = tid >> 2, scg = (tid & 3) * 16;
  u32x4 kr0, kr1, vr0, vr1;
  {
    const u16* kp = kbase + (size_t)srow * 2048 + scg;
    kr0 = *(const u32x4*)kp; kr1 = *(const u32x4*)(kp + 8);
    const u16* vp = vbase + (size_t)srow * S_LEN + scg;
    vr0 = *(const u32x4*)vp; vr1 = *(const u32x4*)(vp + 8);
  }

  for (int t = 0; t < nt; t++) {
    const int kv0 = t * 64;
    __syncthreads();  // everyone done reading previous tile
    *(u32x4*)&Ks[swz(srow, scg)]     = kr0;
    *(u32x4*)&Ks[swz(srow, scg + 8)] = kr1;
    *(u32x4*)&Vs[swz(srow, scg)]     = vr0;
    *(u32x4*)&Vs[swz(srow, scg + 8)] = vr1;
    __syncthreads();  // tile ready
    if (t + 1 < nt) {  // register prefetch of next tile drains under compute
      const u16* kp = kbase + (size_t)(kv0 + 64 + srow) * 2048 + scg;
      kr0 = *(const u32x4*)kp; kr1 = *(const u32x4*)(kp + 8);
      const u16* vp = vbase + (size_t)srow * S_LEN + kv0 + 64 + scg;
      vr0 = *(const u32x4*)vp; vr1 = *(const u32x4*)(vp + 8);
    }

    // QK^T: 16 q rows x 64 kv per wave (Q pre-scaled by QSCALE)
    f32x4 sc[4];
#pragma unroll
    for (int n = 0; n < 4; n++) {
      bf16x8 kf0 = *(const bf16x8*)&Ks[swz(n * 16 + l15, l16 * 8)];
      bf16x8 kf1 = *(const bf16x8*)&Ks[swz(n * 16 + l15, 32 + l16 * 8)];
      f32x4 z = {0.f, 0.f, 0.f, 0.f};
      z = __builtin_amdgcn_mfma_f32_16x16x32_bf16(qa[0], kf0, z, 0, 0, 0);
      sc[n] = __builtin_amdgcn_mfma_f32_16x16x32_bf16(qa[1], kf1, z, 0, 0, 0);
    }

    // P = exp2(s - 16); causal mask only on the diagonal tile
    const bool diag = (t == nt - 1);
#pragma unroll
    for (int n = 0; n < 4; n++)
#pragma unroll
      for (int r = 0; r < 4; r++) {
        float s = sc[n][r];
        if (diag && (kv0 + n * 16 + l15 > wq0 + l16 * 4 + r)) s = -1e30f;
        float p = vexp2(s - 16.0f);
        Ps[w][swz(l16 * 4 + r, n * 16 + l15)] = f2bf(p);
      }

    // PV + row-sum: A = P (16q x 64kv), B^T = V^T. Same-wave LDS, no barrier.
#pragma unroll
    for (int ks = 0; ks < 2; ks++) {
      bf16x8 pa = *(const bf16x8*)&Ps[w][swz(l15, ks * 32 + l16 * 8)];
      osl = __builtin_amdgcn_mfma_f32_16x16x32_bf16(pa, vone, osl, 0, 0, 0);
#pragma unroll
      for (int n = 0; n < 4; n++) {
        bf16x8 vb = *(const bf16x8*)&Vs[swz(n * 16 + l15, ks * 32 + l16 * 8)];
        osum[n] = __builtin_amdgcn_mfma_f32_16x16x32_bf16(pa, vb, osum[n], 0, 0, 0);
      }
    }
  }

  f32x4 inv;
#pragma unroll
  for (int r = 0; r < 4; r++) inv[r] = 1.0f / osl[r];
  u16* ob = aout + (size_t)b * S_LEN * DMODEL + h * 64;
#pragma unroll
  for (int n = 0; n < 4; n++)
#pragma unroll
    for (int r = 0; r < 4; r++) {
      int s = wq0 + l16 * 4 + r;
      ob[(size_t)s * DMODEL + n * 16 + l15] = f2bf(osum[n][r] * inv[r]);
    }
}

extern "C" void kernel_launch(void* const* d_in, const int* in_sizes, int n_in,
                              void* d_out, int out_size, void* d_ws, size_t ws_size,
                              hipStream_t stream) {
  const float* x = (const float*)d_in[0];
  const int* pos = (const int*)d_in[1];
  const float* wqkv = (const float*)d_in[2];
  const float* wout = (const float*)d_in[3];
  float* out = (float*)d_out;
  char* ws = (char*)d_ws;

  // workspace layout (bytes) — ~50.9 MB total
  u16* qkb   = (u16*)(ws);                      // [4096][2048] q,k  16,777,216
  u16* vtb   = (u16*)(ws + 16777216);           // [2][16][64][2048]  8,388,608
  u16* aoutb = (u16*)(ws + 25165824);           // [4096][1024]       8,388,608
  u16* xb    = (u16*)(ws + 33554432);           //                    8,388,608
  u16* wqb   = (u16*)(ws + 41943040);           //                    6,291,456
  u16* wob   = (u16*)(ws + 48234496);           //                    2,097,152
  float2* tab = (float2*)(ws + 50331648);       // 2048*32*8   =      524,288
  (void)ws_size;

  k_cvt_all<<<4096, 256, 0, stream>>>(x, wqkv, wout, xb, wqb, wob);
  k_rope_tab<<<65536 / 256, 256, 0, stream>>>(pos, tab);

  // GEMM1: 16 mb x 12 nb = 192 blocks, tile 256x256, RoPE fused
  k_gemm8<1><<<192, 512, 0, stream>>>(xb, wqb, qkb, vtb, tab, 12);

  dim3 ga(2 * NHEAD, S_LEN / 64);  // x = bh (fast, XCD spread), y = qtile slot
  k_attn<<<ga, 256, 0, stream>>>(qkb, vtb, aoutb);

  // GEMM2: 16 mb x 4 nb = 64 blocks, tile 256x256
  k_gemm8<0><<<64, 512, 0, stream>>>(aoutb, wob, out, nullptr, nullptr, 4);
}